// Round 4
// baseline (614.762 us; speedup 1.0000x reference)
//
#include <hip/hip_runtime.h>
#include <hip/hip_bf16.h>
#include <hip/hip_cooperative_groups.h>

namespace cg = cooperative_groups;

// LightGCN layer: out[v] = sum_{(u->v)} w * x[u], N=100K, E=1.6M, D=128, fp32.
//
// R4: R3 (379us) had gather=117us and ~262us of build across a 8-deep
// dependent dispatch chain -> suspect inter-dispatch overhead + tiny kernels.
// Changes:
//   - ONE cooperative build kernel (zero -> hist -> partials -> scan ->
//     rescan/off/zero-cnt -> build_csr) with grid.sync() between phases.
//     512 blocks x 256 thr (co-resident). Dispatches: 8 -> 2.
//   - gather: full wave per node, two 32-lane halves on alternating CSR
//     entries, unroll x2 => 4 x-rows in flight per wave; __shfl_xor(32)
//     combine. build_csr phase vectorized 2 edges/thread.
// No fp atomics. Fallback to R1 atomic scatter if ws too small.

constexpr int D_FEAT = 128;
constexpr int BUILD_BLOCKS = 512;   // must stay co-resident; 512*4 waves fits

// ---------------- fallback (R1) ----------------
__global__ __launch_bounds__(256) void scatter_atomic_kernel(
    const float* __restrict__ x, const float* __restrict__ w,
    const int* __restrict__ src_idx, const int* __restrict__ dst_idx,
    float* __restrict__ out, int n_edges) {
  long long tid = (long long)blockIdx.x * blockDim.x + threadIdx.x;
  int lane = (int)(tid & 31);
  long long e = tid >> 5;
  if (e >= n_edges) return;
  int s = src_idx[e];
  int d = dst_idx[e];
  float wt = w[e];
  float4 v = ((const float4*)(x + (size_t)s * D_FEAT))[lane];
  float* o = out + (size_t)d * D_FEAT + (size_t)lane * 4;
  atomicAdd(o + 0, v.x * wt);
  atomicAdd(o + 1, v.y * wt);
  atomicAdd(o + 2, v.z * wt);
  atomicAdd(o + 3, v.w * wt);
}

// block-wide exclusive scan over 256 threads; sh must hold >=5 ints.
// Returns exclusive prefix; writes block total to *total if non-null.
__device__ __forceinline__ int block_excl_scan_256(int v, int* sh, int* total) {
  const int lane = threadIdx.x & 63;
  const int wid = threadIdx.x >> 6;
  int inc = v;
  #pragma unroll
  for (int o = 1; o < 64; o <<= 1) {
    int t = __shfl_up(inc, o, 64);
    if (lane >= o) inc += t;
  }
  if (lane == 63) sh[wid] = inc;
  __syncthreads();
  if (threadIdx.x == 0) {
    int a = 0;
    #pragma unroll
    for (int k = 0; k < 4; ++k) { int t = sh[k]; sh[k] = a; a += t; }
    sh[4] = a;
  }
  __syncthreads();
  int r = sh[wid] + inc - v;
  if (total) *total = sh[4];
  __syncthreads();   // sh reusable after return
  return r;
}

// ---------------- fused build (cooperative) ----------------
__global__ __launch_bounds__(256) void build_all_kernel(
    const int* __restrict__ src, const int* __restrict__ dst,
    const float* __restrict__ w, int* __restrict__ cnt,
    int* __restrict__ off, int* __restrict__ bsum, uint2* __restrict__ csr,
    int n_nodes, int n_edges) {
  cg::grid_group grid = cg::this_grid();
  __shared__ int sh[5];
  const int tid = threadIdx.x;
  const int gid = blockIdx.x * blockDim.x + tid;
  const int gsize = gridDim.x * blockDim.x;

  // phase 0: zero cnt
  for (int i = gid; i < n_nodes; i += gsize) cnt[i] = 0;
  grid.sync();

  // phase 1: histogram of dst (int4 loads)
  {
    int e4 = n_edges >> 2;
    for (int i = gid; i < e4; i += gsize) {
      int4 d = ((const int4*)dst)[i];
      atomicAdd(&cnt[d.x], 1);
      atomicAdd(&cnt[d.y], 1);
      atomicAdd(&cnt[d.z], 1);
      atomicAdd(&cnt[d.w], 1);
    }
    for (int i = (e4 << 2) + gid; i < n_edges; i += gsize)
      atomicAdd(&cnt[dst[i]], 1);
  }
  grid.sync();

  // phase 2a: per-block partial sums over contiguous cnt ranges
  const int range = (n_nodes + gridDim.x - 1) / gridDim.x;
  const int base = blockIdx.x * range;
  const int lim = min(base + range, n_nodes);
  {
    int s = 0;
    for (int i = base + tid; i < lim; i += blockDim.x) s += cnt[i];
    const int lane = tid & 63;
    const int wid = tid >> 6;
    #pragma unroll
    for (int o = 32; o >= 1; o >>= 1) s += __shfl_down(s, o, 64);
    if (lane == 0) sh[wid] = s;
    __syncthreads();
    if (tid == 0) bsum[blockIdx.x] = sh[0] + sh[1] + sh[2] + sh[3];
    __syncthreads();
  }
  grid.sync();

  // phase 2b: block 0 exclusive-scans bsum[0..gridDim.x) (2 per thread)
  if (blockIdx.x == 0) {
    int2 v = ((int2*)bsum)[tid];               // gridDim.x == 512
    int s = v.x + v.y;
    int ex = block_excl_scan_256(s, sh, nullptr);
    ((int2*)bsum)[tid] = make_int2(ex, ex + v.x);
  }
  grid.sync();

  // phase 2c: rescan own range -> off, zero cnt (cursor reuse)
  {
    const int bprefix = bsum[blockIdx.x];
    int carry = 0;
    for (int t0 = base; t0 < base + range; t0 += blockDim.x) {
      int i = t0 + tid;
      int c = (i < lim) ? cnt[i] : 0;
      int tot;
      int ex = block_excl_scan_256(c, sh, &tot);
      if (i < lim) {
        off[i] = bprefix + carry + ex;
        cnt[i] = 0;
      }
      carry += tot;
    }
    if (gid == 0) off[n_nodes] = n_edges;
  }
  grid.sync();

  // phase 3: build packed CSR (2 edges/thread)
  {
    int e2 = n_edges >> 1;
    for (int i = gid; i < e2; i += gsize) {
      int2 d = ((const int2*)dst)[i];
      int2 s2 = ((const int2*)src)[i];
      float2 w2 = ((const float2*)w)[i];
      int p0 = off[d.x] + atomicAdd(&cnt[d.x], 1);
      csr[p0] = make_uint2((unsigned)s2.x, __float_as_uint(w2.x));
      int p1 = off[d.y] + atomicAdd(&cnt[d.y], 1);
      csr[p1] = make_uint2((unsigned)s2.y, __float_as_uint(w2.y));
    }
    for (int i = (e2 << 1) + gid; i < n_edges; i += gsize) {
      int d = dst[i];
      int pos = off[d] + atomicAdd(&cnt[d], 1);
      csr[pos] = make_uint2((unsigned)src[i], __float_as_uint(w[i]));
    }
  }
}

// ---------------- gather: 1 wave/node, halves on alternating edges ---------
__global__ __launch_bounds__(256) void gather_kernel(
    const float* __restrict__ x, const int* __restrict__ off,
    const uint2* __restrict__ csr, float* __restrict__ out, int n_nodes) {
  int node = blockIdx.x * 4 + (threadIdx.x >> 6);
  if (node >= n_nodes) return;
  int lane = threadIdx.x & 63;
  int f = lane & 31;       // which float4 of the 128-feat row
  int half = lane >> 5;    // 0/1: alternating CSR entries
  int beg = off[node];
  int end = off[node + 1];
  const float4* X = (const float4*)x;
  float4 a0 = make_float4(0.f, 0.f, 0.f, 0.f);
  float4 a1 = make_float4(0.f, 0.f, 0.f, 0.f);
  int j = beg + half;
  for (; j + 2 < end; j += 4) {
    uint2 e0 = csr[j];
    uint2 e1 = csr[j + 2];
    float4 v0 = X[(size_t)e0.x * 32 + f];
    float4 v1 = X[(size_t)e1.x * 32 + f];
    float w0 = __uint_as_float(e0.y);
    float w1 = __uint_as_float(e1.y);
    a0.x += w0 * v0.x; a0.y += w0 * v0.y; a0.z += w0 * v0.z; a0.w += w0 * v0.w;
    a1.x += w1 * v1.x; a1.y += w1 * v1.y; a1.z += w1 * v1.z; a1.w += w1 * v1.w;
  }
  if (j < end) {
    uint2 e0 = csr[j];
    float4 v0 = X[(size_t)e0.x * 32 + f];
    float w0 = __uint_as_float(e0.y);
    a0.x += w0 * v0.x; a0.y += w0 * v0.y; a0.z += w0 * v0.z; a0.w += w0 * v0.w;
  }
  a0.x += a1.x; a0.y += a1.y; a0.z += a1.z; a0.w += a1.w;
  // combine the two halves (lanes i and i+32 hold partial sums of same f)
  a0.x += __shfl_xor(a0.x, 32, 64);
  a0.y += __shfl_xor(a0.y, 32, 64);
  a0.z += __shfl_xor(a0.z, 32, 64);
  a0.w += __shfl_xor(a0.w, 32, 64);
  if (half == 0) ((float4*)out)[(size_t)node * 32 + f] = a0;
}

extern "C" void kernel_launch(void* const* d_in, const int* in_sizes, int n_in,
                              void* d_out, int out_size, void* d_ws, size_t ws_size,
                              hipStream_t stream) {
  const float* x  = (const float*)d_in[0];
  const float* w  = (const float*)d_in[1];
  const int* eidx = (const int*)d_in[2];

  int n_edges = in_sizes[1];           // E
  int n_nodes = out_size / D_FEAT;     // N
  const int* src = eidx;
  const int* dst = eidx + n_edges;
  float* out = (float*)d_out;

  // workspace layout (8B aligned segments):
  //   off:  N+2 ints, cnt: N ints (N assumed even; pad below), bsum: 512,
  //   csr:  E uint2
  const int n_off = (n_nodes + 2 + 1) & ~1;
  const int n_cnt = (n_nodes + 1) & ~1;
  size_t need = ((size_t)n_off + n_cnt + BUILD_BLOCKS) * 4 + (size_t)n_edges * 8;
  if (ws_size < need) {
    hipMemsetAsync(d_out, 0, (size_t)out_size * sizeof(float), stream);
    long long total_threads = (long long)n_edges * 32;
    long long grid = (total_threads + 255) / 256;
    scatter_atomic_kernel<<<(dim3)(unsigned)grid, 256, 0, stream>>>(
        x, w, src, dst, out, n_edges);
    return;
  }

  int* off_arr = (int*)d_ws;                 // N+2 (padded even)
  int* cnt     = off_arr + n_off;            // N (padded even)
  int* bsum    = cnt + n_cnt;                // 512
  uint2* csr   = (uint2*)(bsum + BUILD_BLOCKS);  // E

  void* args[] = {(void*)&src, (void*)&dst, (void*)&w, (void*)&cnt,
                  (void*)&off_arr, (void*)&bsum, (void*)&csr,
                  (void*)&n_nodes, (void*)&n_edges};
  hipLaunchCooperativeKernel((const void*)build_all_kernel,
                             dim3(BUILD_BLOCKS), dim3(256), args, 0, stream);

  int gblocks = (n_nodes + 3) / 4;
  gather_kernel<<<gblocks, 256, 0, stream>>>(x, off_arr, csr, out, n_nodes);
}

// Round 6
// 363.313 us; speedup vs baseline: 1.6921x; 1.6921x over previous
//
#include <hip/hip_runtime.h>
#include <hip/hip_bf16.h>

// LightGCN layer: out[v] = sum_{(u->v)} w * x[u], N=100K, E=1.6M, D=128, fp32.
//
// R5b: R5 with compile fix — __builtin_nontemporal_store needs a NATIVE
// vector type (ext_vector_type), not HIP's float4 class. Strategy unchanged:
//   - single-pass decoupled-lookback scan (1 kernel replaces 3); tile=2048
//   - build_csr: 2 edges/thread (int2/float2)
//   - gather: 2 halves x unroll4 = 8 x-rows in flight per wave; nontemporal
//     out stores (out is write-once, keep x in L2)
// Dispatches: memset -> hist -> scan -> build_csr -> gather (5 total).

constexpr int D_FEAT = 128;
constexpr int SCAN_TILE = 2048;   // 256 threads x 8 elements

typedef float v4f __attribute__((ext_vector_type(4)));

// ---------------- fallback (R1) ----------------
__global__ __launch_bounds__(256) void scatter_atomic_kernel(
    const float* __restrict__ x, const float* __restrict__ w,
    const int* __restrict__ src_idx, const int* __restrict__ dst_idx,
    float* __restrict__ out, int n_edges) {
  long long tid = (long long)blockIdx.x * blockDim.x + threadIdx.x;
  int lane = (int)(tid & 31);
  long long e = tid >> 5;
  if (e >= n_edges) return;
  int s = src_idx[e];
  int d = dst_idx[e];
  float wt = w[e];
  float4 v = ((const float4*)(x + (size_t)s * D_FEAT))[lane];
  float* o = out + (size_t)d * D_FEAT + (size_t)lane * 4;
  atomicAdd(o + 0, v.x * wt);
  atomicAdd(o + 1, v.y * wt);
  atomicAdd(o + 2, v.z * wt);
  atomicAdd(o + 3, v.w * wt);
}

// ---------------- phase 1: histogram (int4 dst loads) ----------------
__global__ __launch_bounds__(256) void hist_kernel(
    const int* __restrict__ dst, int* __restrict__ cnt, int n_edges) {
  int i = blockIdx.x * blockDim.x + threadIdx.x;
  int base = i * 4;
  if (base + 3 < n_edges) {
    int4 d = ((const int4*)dst)[i];
    atomicAdd(&cnt[d.x], 1);
    atomicAdd(&cnt[d.y], 1);
    atomicAdd(&cnt[d.z], 1);
    atomicAdd(&cnt[d.w], 1);
  } else {
    for (int k = base; k < n_edges; ++k) atomicAdd(&cnt[dst[k]], 1);
  }
}

// block-wide exclusive scan over 256 threads; sh holds >=5 ints.
__device__ __forceinline__ int block_excl_scan_256(int v, int* sh, int* total) {
  const int lane = threadIdx.x & 63;
  const int wid = threadIdx.x >> 6;
  int inc = v;
  #pragma unroll
  for (int o = 1; o < 64; o <<= 1) {
    int t = __shfl_up(inc, o, 64);
    if (lane >= o) inc += t;
  }
  if (lane == 63) sh[wid] = inc;
  __syncthreads();
  if (threadIdx.x == 0) {
    int a = 0;
    #pragma unroll
    for (int k = 0; k < 4; ++k) { int t = sh[k]; sh[k] = a; a += t; }
    sh[4] = a;
  }
  __syncthreads();
  int r = sh[wid] + inc - v;
  if (total) *total = sh[4];
  __syncthreads();
  return r;
}

// ---------------- phase 2: single-pass lookback scan ----------------
// cnt -> off (exclusive), zero cnt. tstate[b] = (state<<32)|value:
// state 0=invalid, 1=aggregate, 2=inclusive-prefix. Zeroed by host memset.
__global__ __launch_bounds__(256) void scan_lookback_kernel(
    int* __restrict__ cnt, int* __restrict__ off,
    unsigned long long* __restrict__ tstate, int n, int n_edges) {
  __shared__ int sh[5];
  __shared__ int s_prefix;
  const int tid = threadIdx.x;
  const int b = blockIdx.x;
  const int base = b * SCAN_TILE + tid * 8;

  int c[8];
  const bool full = (base + 8 <= n);
  if (full) {
    int4 a = ((const int4*)(cnt + base))[0];
    int4 d = ((const int4*)(cnt + base))[1];
    c[0] = a.x; c[1] = a.y; c[2] = a.z; c[3] = a.w;
    c[4] = d.x; c[5] = d.y; c[6] = d.z; c[7] = d.w;
  } else {
    #pragma unroll
    for (int k = 0; k < 8; ++k) c[k] = (base + k < n) ? cnt[base + k] : 0;
  }
  int p[8];
  int tsum = 0;
  #pragma unroll
  for (int k = 0; k < 8; ++k) { p[k] = tsum; tsum += c[k]; }

  int total;
  int tex = block_excl_scan_256(tsum, sh, &total);

  if (tid == 0) {
    int excl = 0;
    if (b == 0) {
      __hip_atomic_store(&tstate[0], (2ULL << 32) | (unsigned)total,
                         __ATOMIC_RELEASE, __HIP_MEMORY_SCOPE_AGENT);
    } else {
      __hip_atomic_store(&tstate[b], (1ULL << 32) | (unsigned)total,
                         __ATOMIC_RELEASE, __HIP_MEMORY_SCOPE_AGENT);
      int pidx = b - 1;
      int run = 0;
      while (true) {
        unsigned long long v = __hip_atomic_load(
            &tstate[pidx], __ATOMIC_ACQUIRE, __HIP_MEMORY_SCOPE_AGENT);
        unsigned st = (unsigned)(v >> 32);
        if (st == 0u) { __builtin_amdgcn_s_sleep(1); continue; }
        run += (int)(unsigned)v;
        if (st == 2u) break;
        --pidx;
      }
      excl = run;
      __hip_atomic_store(&tstate[b],
                         (2ULL << 32) | (unsigned)(excl + total),
                         __ATOMIC_RELEASE, __HIP_MEMORY_SCOPE_AGENT);
    }
    s_prefix = excl;
  }
  __syncthreads();

  int myoff = s_prefix + tex;
  if (full) {
    ((int4*)(off + base))[0] =
        make_int4(myoff + p[0], myoff + p[1], myoff + p[2], myoff + p[3]);
    ((int4*)(off + base))[1] =
        make_int4(myoff + p[4], myoff + p[5], myoff + p[6], myoff + p[7]);
    ((int4*)(cnt + base))[0] = make_int4(0, 0, 0, 0);
    ((int4*)(cnt + base))[1] = make_int4(0, 0, 0, 0);
  } else {
    #pragma unroll
    for (int k = 0; k < 8; ++k)
      if (base + k < n) { off[base + k] = myoff + p[k]; cnt[base + k] = 0; }
  }
  if (b == 0 && tid == 0) off[n] = n_edges;  // sum(hist)==E, all dst in [0,N)
}

// ---------------- phase 3: build packed CSR (2 edges/thread) ---------------
__global__ __launch_bounds__(256) void build_csr_kernel(
    const int* __restrict__ src, const int* __restrict__ dst,
    const float* __restrict__ w, const int* __restrict__ off,
    int* __restrict__ cur, uint2* __restrict__ csr, int n_edges) {
  int i = blockIdx.x * blockDim.x + threadIdx.x;
  int e2 = n_edges >> 1;
  if (i < e2) {
    int2 d = ((const int2*)dst)[i];
    int2 s2 = ((const int2*)src)[i];
    float2 w2 = ((const float2*)w)[i];
    int p0 = off[d.x] + atomicAdd(&cur[d.x], 1);
    csr[p0] = make_uint2((unsigned)s2.x, __float_as_uint(w2.x));
    int p1 = off[d.y] + atomicAdd(&cur[d.y], 1);
    csr[p1] = make_uint2((unsigned)s2.y, __float_as_uint(w2.y));
  } else if (i == e2 && (n_edges & 1)) {
    int e = n_edges - 1;
    int d = dst[e];
    int pos = off[d] + atomicAdd(&cur[d], 1);
    csr[pos] = make_uint2((unsigned)src[e], __float_as_uint(w[e]));
  }
}

// ---------------- phase 4: gather (2 halves x unroll4) ----------------
__global__ __launch_bounds__(256) void gather_kernel(
    const float* __restrict__ x, const int* __restrict__ off,
    const uint2* __restrict__ csr, float* __restrict__ out, int n_nodes) {
  int node = blockIdx.x * 4 + (threadIdx.x >> 6);
  if (node >= n_nodes) return;
  int lane = threadIdx.x & 63;
  int f = lane & 31;       // which float4 of the 128-feat row
  int half = lane >> 5;    // 0/1: alternating CSR entries
  int beg = off[node];
  int end = off[node + 1];
  const float4* X = (const float4*)x;
  float4 a0 = make_float4(0.f, 0.f, 0.f, 0.f);
  float4 a1 = make_float4(0.f, 0.f, 0.f, 0.f);
  float4 a2 = make_float4(0.f, 0.f, 0.f, 0.f);
  float4 a3 = make_float4(0.f, 0.f, 0.f, 0.f);
  int j = beg + half;
  for (; j + 6 < end; j += 8) {   // 4 entries per half, 8 per wave
    uint2 e0 = csr[j];
    uint2 e1 = csr[j + 2];
    uint2 e2 = csr[j + 4];
    uint2 e3 = csr[j + 6];
    float4 v0 = X[(size_t)e0.x * 32 + f];
    float4 v1 = X[(size_t)e1.x * 32 + f];
    float4 v2 = X[(size_t)e2.x * 32 + f];
    float4 v3 = X[(size_t)e3.x * 32 + f];
    float w0 = __uint_as_float(e0.y);
    float w1 = __uint_as_float(e1.y);
    float w2 = __uint_as_float(e2.y);
    float w3 = __uint_as_float(e3.y);
    a0.x += w0 * v0.x; a0.y += w0 * v0.y; a0.z += w0 * v0.z; a0.w += w0 * v0.w;
    a1.x += w1 * v1.x; a1.y += w1 * v1.y; a1.z += w1 * v1.z; a1.w += w1 * v1.w;
    a2.x += w2 * v2.x; a2.y += w2 * v2.y; a2.z += w2 * v2.z; a2.w += w2 * v2.w;
    a3.x += w3 * v3.x; a3.y += w3 * v3.y; a3.z += w3 * v3.z; a3.w += w3 * v3.w;
  }
  for (; j < end; j += 2) {
    uint2 e0 = csr[j];
    float4 v0 = X[(size_t)e0.x * 32 + f];
    float w0 = __uint_as_float(e0.y);
    a0.x += w0 * v0.x; a0.y += w0 * v0.y; a0.z += w0 * v0.z; a0.w += w0 * v0.w;
  }
  a0.x += a1.x + a2.x + a3.x;
  a0.y += a1.y + a2.y + a3.y;
  a0.z += a1.z + a2.z + a3.z;
  a0.w += a1.w + a2.w + a3.w;
  a0.x += __shfl_xor(a0.x, 32, 64);
  a0.y += __shfl_xor(a0.y, 32, 64);
  a0.z += __shfl_xor(a0.z, 32, 64);
  a0.w += __shfl_xor(a0.w, 32, 64);
  if (half == 0) {
    v4f val = {a0.x, a0.y, a0.z, a0.w};
    __builtin_nontemporal_store(val, (v4f*)out + (size_t)node * 32 + f);
  }
}

extern "C" void kernel_launch(void* const* d_in, const int* in_sizes, int n_in,
                              void* d_out, int out_size, void* d_ws, size_t ws_size,
                              hipStream_t stream) {
  const float* x  = (const float*)d_in[0];
  const float* w  = (const float*)d_in[1];
  const int* eidx = (const int*)d_in[2];

  int n_edges = in_sizes[1];           // E
  int n_nodes = out_size / D_FEAT;     // N
  const int* src = eidx;
  const int* dst = eidx + n_edges;
  float* out = (float*)d_out;

  const int ntiles = (n_nodes + SCAN_TILE - 1) / SCAN_TILE;
  const int ntiles_pad = (ntiles + 15) & ~15;        // keep 16B multiples

  // layout (all segment sizes multiples of 4 ints = 16B):
  //   off:    n_off ints (n_nodes+1 used)
  //   cnt:    n_cnt ints   \ one contiguous memset
  //   tstate: ntiles_pad u64 /
  //   csr:    E uint2
  const int n_off = (n_nodes + 2 + 3) & ~3;
  const int n_cnt = (n_nodes + 3) & ~3;
  size_t need = ((size_t)n_off + n_cnt) * 4 + (size_t)ntiles_pad * 8 +
                (size_t)n_edges * 8;
  if (ws_size < need) {
    hipMemsetAsync(d_out, 0, (size_t)out_size * sizeof(float), stream);
    long long total_threads = (long long)n_edges * 32;
    long long grid = (total_threads + 255) / 256;
    scatter_atomic_kernel<<<(dim3)(unsigned)grid, 256, 0, stream>>>(
        x, w, src, dst, out, n_edges);
    return;
  }

  int* off_arr = (int*)d_ws;                                   // n_off
  int* cnt     = off_arr + n_off;                              // n_cnt
  unsigned long long* tstate = (unsigned long long*)(cnt + n_cnt);
  uint2* csr   = (uint2*)(tstate + ntiles_pad);                // E

  // one memset covers cnt + tstate (contiguous)
  hipMemsetAsync(cnt, 0, (size_t)n_cnt * 4 + (size_t)ntiles_pad * 8, stream);

  int hblocks = ((n_edges + 3) / 4 + 255) / 256;
  hist_kernel<<<hblocks, 256, 0, stream>>>(dst, cnt, n_edges);

  scan_lookback_kernel<<<ntiles, 256, 0, stream>>>(cnt, off_arr, tstate,
                                                   n_nodes, n_edges);

  int bthreads = (n_edges >> 1) + 1;
  build_csr_kernel<<<(bthreads + 255) / 256, 256, 0, stream>>>(
      src, dst, w, off_arr, cnt, csr, n_edges);

  int gblocks = (n_nodes + 3) / 4;
  gather_kernel<<<gblocks, 256, 0, stream>>>(x, off_arr, csr, out, n_nodes);
}